// Round 2
// baseline (5006.675 us; speedup 1.0000x reference)
//
#include <hip/hip_runtime.h>
#include <hip/hip_bf16.h>

#define N_MOLS      64
#define N_CONFS_PER 10
#define A_ATOMS     40
#define N_CONFS     640
#define N_ATOMS     25600
#define N_EDGES     409600
#define D           256
#define NG          32
#define NLAYERS     4
#define MOLB        512
#define H_MOL       384
#define EDGE_CAP    1024

// ssp(x) = softplus(x) - ln2, stable form (matches jax.nn.softplus numerics)
__device__ __forceinline__ float sspf(float x) {
    return fmaxf(x, 0.f) + log1pf(expf(-fabsf(x))) - 0.69314718055994531f;
}

// ---------------- edge bucketing by conformer ----------------
__global__ __launch_bounds__(256) void k_scatter(const int* __restrict__ nbr,
                                                 unsigned* __restrict__ cursors,
                                                 unsigned* __restrict__ esort) {
    int e = blockIdx.x * 256 + threadIdx.x;
    if (e >= N_EDGES) return;
    int a0 = nbr[2 * e], a1 = nbr[2 * e + 1];
    int conf = a0 / A_ATOMS;
    int a0l = a0 - conf * A_ATOMS;
    int a1l = a1 - conf * A_ATOMS;
    unsigned r = atomicAdd(&cursors[conf], 1u);
    if (r < EDGE_CAP) esort[conf * EDGE_CAP + r] = (unsigned)((a0l << 6) | a1l);
}

// dense phase helper: acc[a] = bias + sum_k src[a][k] * W[k*D + c]
__device__ __forceinline__ void mm_phase(const float (*src)[D],
                                         const float* __restrict__ Wc,
                                         float bias, float* acc) {
#pragma unroll
    for (int a = 0; a < A_ATOMS; ++a) acc[a] = bias;
    for (int k = 0; k < D; k += 4) {
        float w0 = Wc[(k + 0) * D];
        float w1 = Wc[(k + 1) * D];
        float w2 = Wc[(k + 2) * D];
        float w3 = Wc[(k + 3) * D];
#pragma unroll
        for (int a = 0; a < A_ATOMS; ++a) {
            const float4 v = *(const float4*)&src[a][k];
            acc[a] = fmaf(v.x, w0, fmaf(v.y, w1, fmaf(v.z, w2, fmaf(v.w, w3, acc[a]))));
        }
    }
}

// ---------------- main per-conformer kernel: 4 layers fully in LDS ----------------
__global__ __launch_bounds__(256) void k_main(
    const int* __restrict__ z, const float* __restrict__ xyz,
    const float* __restrict__ emb,
    const float* __restrict__ We1, const float* __restrict__ be1,
    const float* __restrict__ We2, const float* __restrict__ be2,
    const float* __restrict__ Wn,  const float* __restrict__ bn,
    const float* __restrict__ Wu1, const float* __restrict__ bu1,
    const float* __restrict__ Wu2, const float* __restrict__ bu2,
    const unsigned* __restrict__ cursors, const unsigned* __restrict__ esort,
    float* __restrict__ conf_fp)
{
    __shared__ float sR[A_ATOMS][D];   // residual stream r
    __shared__ float sB[A_ATOMS][D];   // rn, later t = ssp(agg@Wu1+bu1)
    __shared__ float sA[A_ATOMS][D];   // agg
    __shared__ float sXYZ[A_ATOMS][3];
    __shared__ float sEG[32][NG];
    __shared__ float sH[32][NG];
    __shared__ int   sE0[32];
    __shared__ int   sE1[32];
    __shared__ float sD[32];
    __shared__ int   sZ[A_ATOMS];

    const int conf = blockIdx.x;
    const int c = threadIdx.x;

    if (c < A_ATOMS) {
        int ga = conf * A_ATOMS + c;
        sZ[c] = z[ga];
        sXYZ[c][0] = xyz[ga * 3 + 0];
        sXYZ[c][1] = xyz[ga * 3 + 1];
        sXYZ[c][2] = xyz[ga * 3 + 2];
    }
    __syncthreads();
#pragma unroll
    for (int a = 0; a < A_ATOMS; ++a)
        sR[a][c] = emb[sZ[a] * D + c];

    int cnt = (int)cursors[conf];
    if (cnt > EDGE_CAP) cnt = EDGE_CAP;
    const unsigned* eptr = esort + conf * EDGE_CAP;

    for (int l = 0; l < NLAYERS; ++l) {
        __syncthreads();
        // ---- Phase A: sB = r @ Wn[l] + bn[l]; zero agg
        {
            float acc[A_ATOMS];
            mm_phase(sR, Wn + (size_t)l * D * D + c, bn[l * D + c], acc);
#pragma unroll
            for (int a = 0; a < A_ATOMS; ++a) { sB[a][c] = acc[a]; sA[a][c] = 0.f; }
        }
        __syncthreads();
        // ---- Phase B: edges (batches of 32), ef fused, column-owned scatter
        {
            const int t = c & 31;
            float we1col[NG], we2col[NG];
#pragma unroll
            for (int m = 0; m < NG; ++m) we1col[m] = We1[((size_t)l * NG + m) * NG + t];
#pragma unroll
            for (int m = 0; m < NG; ++m) we2col[m] = We2[((size_t)l * NG + m) * D + c];
            const float be1t = be1[l * NG + t];
            const float be2c = be2[l * D + c];

            for (int base = 0; base < cnt; base += 32) {
                const int nb = min(32, cnt - base);
                if (c < nb) {
                    unsigned pe = eptr[base + c];
                    int a0l = (pe >> 6) & 63, a1l = pe & 63;
                    sE0[c] = a0l; sE1[c] = a1l;
                    float dx = sXYZ[a0l][0] - sXYZ[a1l][0];
                    float dy = sXYZ[a0l][1] - sXYZ[a1l][1];
                    float dz = sXYZ[a0l][2] - sXYZ[a1l][2];
                    sD[c] = sqrtf(dx * dx + dy * dy + dz * dz);
                }
                __syncthreads();
                {   // e_g: 32 edges x 32 gaussians, 4 per thread
                    int e = c >> 3;
                    if (e < nb) {
                        float dd = sD[e];
                        int m0 = (c & 7) << 2;
#pragma unroll
                        for (int mm = 0; mm < 4; ++mm) {
                            int m = m0 + mm;
                            float u = (dd - (float)m * (5.0f / 31.0f)) * (31.0f / 5.0f);
                            sEG[e][m] = expf(-0.5f * u * u);
                        }
                    }
                }
                __syncthreads();
                // h = ssp(e_g @ We1 + be1): each thread does comp t for 4 edges
#pragma unroll
                for (int eb = 0; eb < 4; ++eb) {
                    int e = (c >> 5) + eb * 8;
                    if (e < nb) {
                        float s = be1t;
#pragma unroll
                        for (int m = 0; m < NG; m += 4) {
                            const float4 g = *(const float4*)&sEG[e][m];
                            s = fmaf(g.x, we1col[m], s);
                            s = fmaf(g.y, we1col[m + 1], s);
                            s = fmaf(g.z, we1col[m + 2], s);
                            s = fmaf(g.w, we1col[m + 3], s);
                        }
                        sH[e][t] = sspf(s);
                    }
                }
                __syncthreads();
                // ef_c = h @ We2[:,c] + be2[c]; agg scatter (column c owned by this thread)
                for (int e = 0; e < nb; ++e) {
                    float ef = be2c;
#pragma unroll
                    for (int m = 0; m < NG; m += 4) {
                        const float4 h4 = *(const float4*)&sH[e][m];
                        ef = fmaf(h4.x, we2col[m], ef);
                        ef = fmaf(h4.y, we2col[m + 1], ef);
                        ef = fmaf(h4.z, we2col[m + 2], ef);
                        ef = fmaf(h4.w, we2col[m + 3], ef);
                    }
                    int a0l = sE0[e], a1l = sE1[e];
                    float r0 = sB[a0l][c], r1 = sB[a1l][c];
                    sA[a0l][c] += r1 * ef;
                    sA[a1l][c] += r0 * ef;
                }
                __syncthreads();
            }
        }
        // ---- Phase C1: sB = ssp(agg @ Wu1 + bu1)
        {
            float acc[A_ATOMS];
            mm_phase(sA, Wu1 + (size_t)l * D * D + c, bu1[l * D + c], acc);
#pragma unroll
            for (int a = 0; a < A_ATOMS; ++a) sB[a][c] = sspf(acc[a]);
        }
        __syncthreads();
        // ---- Phase C2: r += sB @ Wu2 + bu2
        {
            float acc[A_ATOMS];
            mm_phase(sB, Wu2 + (size_t)l * D * D + c, bu2[l * D + c], acc);
#pragma unroll
            for (int a = 0; a < A_ATOMS; ++a) sR[a][c] += acc[a];
        }
    }
    __syncthreads();
    float s = 0.f;
#pragma unroll
    for (int a = 0; a < A_ATOMS; ++a) s += sR[a][c];
    conf_fp[conf * D + c] = s;
}

// ---------------- per-conformer molecular MLP + Boltzmann-weighted reduce ----------------
__global__ __launch_bounds__(512) void k_mol(
    const float* __restrict__ conf_fp,
    const float* __restrict__ Wm1, const float* __restrict__ bm1,
    const float* __restrict__ Wm2, const float* __restrict__ bm2,
    const float* __restrict__ boltz, float* __restrict__ mol_fp)
{
    __shared__ float cf[D];
    __shared__ float t[H_MOL];
    const int conf = blockIdx.x;
    const int tid = threadIdx.x;
    if (tid < D) cf[tid] = conf_fp[conf * D + tid];
    __syncthreads();
    if (tid < H_MOL) {
        float s = bm1[tid];
        for (int k = 0; k < D; k += 4) {
            const float4 v = *(const float4*)&cf[k];
            s = fmaf(v.x, Wm1[(k + 0) * H_MOL + tid], s);
            s = fmaf(v.y, Wm1[(k + 1) * H_MOL + tid], s);
            s = fmaf(v.z, Wm1[(k + 2) * H_MOL + tid], s);
            s = fmaf(v.w, Wm1[(k + 3) * H_MOL + tid], s);
        }
        t[tid] = sspf(s);
    }
    __syncthreads();
    {
        const int m = tid;  // 512 threads = MOLB
        float s = bm2[m];
        for (int h = 0; h < H_MOL; h += 4) {
            const float4 v = *(const float4*)&t[h];
            s = fmaf(v.x, Wm2[(h + 0) * MOLB + m], s);
            s = fmaf(v.y, Wm2[(h + 1) * MOLB + m], s);
            s = fmaf(v.z, Wm2[(h + 2) * MOLB + m], s);
            s = fmaf(v.w, Wm2[(h + 3) * MOLB + m], s);
        }
        atomicAdd(&mol_fp[(conf / N_CONFS_PER) * MOLB + m], s * boltz[conf]);
    }
}

// ---------------- final readout MLP + sigmoid ----------------
__global__ __launch_bounds__(256) void k_final(
    const float* __restrict__ mol_fp,
    const float* __restrict__ Wr1, const float* __restrict__ br1,
    const float* __restrict__ Wr2, const float* __restrict__ br2,
    float* __restrict__ out)
{
    __shared__ float mf[MOLB];
    __shared__ float t2[D];
    __shared__ float red[4];
    const int mol = blockIdx.x, tid = threadIdx.x;
    mf[tid]       = mol_fp[mol * MOLB + tid];
    mf[tid + 256] = mol_fp[mol * MOLB + tid + 256];
    __syncthreads();
    {
        float s = br1[tid];
        for (int k = 0; k < MOLB; k += 4) {
            const float4 v = *(const float4*)&mf[k];
            s = fmaf(v.x, Wr1[(k + 0) * D + tid], s);
            s = fmaf(v.y, Wr1[(k + 1) * D + tid], s);
            s = fmaf(v.z, Wr1[(k + 2) * D + tid], s);
            s = fmaf(v.w, Wr1[(k + 3) * D + tid], s);
        }
        t2[tid] = sspf(s);
    }
    __syncthreads();
    float p = t2[tid] * Wr2[tid];
#pragma unroll
    for (int o = 32; o > 0; o >>= 1) p += __shfl_down(p, o);
    if ((tid & 63) == 0) red[tid >> 6] = p;
    __syncthreads();
    if (tid == 0) {
        float logit = red[0] + red[1] + red[2] + red[3] + br2[0];
        out[mol] = 1.f / (1.f + expf(-logit));
    }
}

extern "C" void kernel_launch(void* const* d_in, const int* in_sizes, int n_in,
                              void* d_out, int out_size, void* d_ws, size_t ws_size,
                              hipStream_t stream)
{
    const int*   z     = (const int*)d_in[0];
    const float* xyz   = (const float*)d_in[1];
    const int*   nbr   = (const int*)d_in[2];
    const float* boltz = (const float*)d_in[3];
    const float* emb   = (const float*)d_in[4];
    const float* We1   = (const float*)d_in[5];
    const float* be1   = (const float*)d_in[6];
    const float* We2   = (const float*)d_in[7];
    const float* be2   = (const float*)d_in[8];
    const float* Wn    = (const float*)d_in[9];
    const float* bn    = (const float*)d_in[10];
    const float* Wu1   = (const float*)d_in[11];
    const float* bu1   = (const float*)d_in[12];
    const float* Wu2   = (const float*)d_in[13];
    const float* bu2   = (const float*)d_in[14];
    const float* Wm1   = (const float*)d_in[15];
    const float* bm1   = (const float*)d_in[16];
    const float* Wm2   = (const float*)d_in[17];
    const float* bm2   = (const float*)d_in[18];
    const float* Wr1   = (const float*)d_in[19];
    const float* br1   = (const float*)d_in[20];
    const float* Wr2   = (const float*)d_in[21];
    const float* br2   = (const float*)d_in[22];

    char* ws = (char*)d_ws;
    unsigned* cursors = (unsigned*)ws;                      // 640*4      = 2560 B
    float*    mol_fp  = (float*)(ws + 2560);                // 64*512*4   = 131072 B -> 133632
    unsigned* esort   = (unsigned*)(ws + 133632);           // 640*1024*4 = 2621440 B -> 2755072
    float*    conf_fp = (float*)(ws + 2755072);             // 640*256*4  = 655360 B

    hipMemsetAsync(cursors, 0, 2560 + 131072, stream);      // cursors + mol_fp
    k_scatter<<<(N_EDGES + 255) / 256, 256, 0, stream>>>(nbr, cursors, esort);
    k_main<<<N_CONFS, 256, 0, stream>>>(z, xyz, emb, We1, be1, We2, be2, Wn, bn,
                                        Wu1, bu1, Wu2, bu2, cursors, esort, conf_fp);
    k_mol<<<N_CONFS, 512, 0, stream>>>(conf_fp, Wm1, bm1, Wm2, bm2, boltz, mol_fp);
    k_final<<<N_MOLS, 256, 0, stream>>>(mol_fp, Wr1, br1, Wr2, br2, (float*)d_out);
}